// Round 12
// baseline (383.196 us; speedup 1.0000x reference)
//
#include <hip/hip_runtime.h>

// ScannedRNN (GRU w/ reset masking) T=1024,B=128,H=256 — stream-packed
// segment-parallel scan, v16: gi_gemm double-buffered (T3 2-phase, counted
// vmcnt(6)). scan = v13 winner (180us); fused f32-A + XCD swizzle kept.
//
//   R11 ledger: v15 total 381.8 (best). gemm ~155us, MfmaUtil ~7% —
//   latency-bound: single-buffered staging exposes full global-load latency
//   every K-step (stage -> syncthreads vmcnt(0) -> compute, x8). v16:
//   issue K-step k+1's 6 gload_lds BEFORE computing step k; raw barriers;
//   s_waitcnt vmcnt(6) waits only the year-old batch (6 newer ride). Last
//   iter stages a dummy wrapped tile to keep the count constant. LDS
//   24->48KB (3 blocks/CU). Note (R11 lesson): with 128B row stride all
//   rows start at bank 0 -> 8 lanes/16B-slot is the floor; v15's swizzle
//   already reaches it (A was 16-way before, B 4-way).
//
// Column permutation: c' = 48*(u>>4) + g*16 + (u&15), g in {r,z,n}. Wave w
// owns c' [96w,96w+96) = u in [32w,32w+32) with complete gate triples.

typedef _Float16 half2_t __attribute__((ext_vector_type(2)));
typedef _Float16 half4_t __attribute__((ext_vector_type(4)));
typedef _Float16 half8_t __attribute__((ext_vector_type(8)));
typedef float f32x4 __attribute__((ext_vector_type(4)));

#define T_DIM 1024
#define B_DIM 128
#define H_DIM 256
#define N3 768
#define NSTREAM 4096    // 256 blocks x 16 rows
#define ROWS 16

__device__ __forceinline__ int perm_n(int cp) {
  int ublk = cp / 48;
  int rem = cp % 48;
  int g = rem >> 4;
  int u4 = rem & 15;
  return g * 256 + ublk * 16 + u4;
}

// ---------------- prepack ----------------

__global__ void prep_whb(const float* __restrict__ Wh, unsigned* __restrict__ WhB) {
  int i = blockIdx.x * 256 + threadIdx.x;   // 0..98303 (dword = 2 halves)
  int h = 2 * i;
  int idx = h & 7;
  int lane = (h >> 3) & 63;
  int ntk = h >> 9;
  int nt = ntk % 48;
  int kt = ntk / 48;
  int k = kt * 32 + ((lane >> 4) * 8) + idx;
  int n = perm_n(nt * 16 + (lane & 15));
  half2_t p;
  p.x = (_Float16)Wh[(size_t)k * N3 + n];
  p.y = (_Float16)Wh[(size_t)(k + 1) * N3 + n];
  WhB[i] = __builtin_bit_cast(unsigned, p);
}

__global__ void prep_witp(const float* __restrict__ Wi, _Float16* __restrict__ WiTp) {
  int i = blockIdx.x * 256 + threadIdx.x;   // 0..196607
  int cp = i >> 8;
  int k = i & 255;
  WiTp[(size_t)cp * 256 + k] = (_Float16)Wi[(size_t)k * N3 + perm_n(cp)];
}

__global__ void prep_bip(const float* __restrict__ bi, float* __restrict__ bip) {
  int i = threadIdx.x;
  bip[i] = bi[perm_n(i)];
}

__global__ void init_h(const float* __restrict__ h0, float* __restrict__ h_state) {
  int i = blockIdx.x * 256 + threadIdx.x;
  h_state[i] = h0[i];
}

// ---------------- segment extraction ----------------

__global__ void seg_transpose(const int* __restrict__ resets, int* __restrict__ resT) {
  int i = blockIdx.x * 256 + threadIdx.x;   // 0..131071
  int b = i >> 10;
  int t = i & 1023;
  resT[i] = resets[(size_t)t * B_DIM + b];
}

// rec: start(10) | len(11)<<10 | rankInRowLen(10)<<21 | carry(1)<<31
__global__ __launch_bounds__(256) void seg_extract(
    const int* __restrict__ resT, int t0, int steps,
    unsigned* __restrict__ rowsegs, unsigned* __restrict__ rowcnt,
    unsigned* __restrict__ lhist) {
  const int b = blockIdx.x;
  const int tid = threadIdx.x;
  const int lane = tid & 63;
  const int w = tid >> 6;
  const int per = (steps + 255) >> 8;

  __shared__ unsigned short sstartL[1025];
  __shared__ unsigned lcur[1025];
  __shared__ unsigned wsum[4];

  for (int l = tid; l <= steps; l += 256) lcur[l] = 0;

  const int* rrow = resT + (size_t)b * T_DIM + t0;
  int myfirst = tid * per;
  unsigned cnt = 0;
  for (int i = 0; i < per; ++i) {
    int s = myfirst + i;
    if (s < steps && (s == 0 || rrow[s] != 0)) cnt++;
  }
  unsigned pre = cnt;
#pragma unroll
  for (int off = 1; off < 64; off <<= 1) {
    unsigned v = __shfl_up(pre, off);
    if (lane >= off) pre += v;
  }
  if (lane == 63) wsum[w] = pre;
  __syncthreads();
  unsigned wbase = 0, total = 0;
#pragma unroll
  for (int i = 0; i < 4; ++i) {
    if (i < w) wbase += wsum[i];
    total += wsum[i];
  }
  unsigned r = wbase + pre - cnt;
  for (int i = 0; i < per; ++i) {
    int s = myfirst + i;
    if (s < steps && (s == 0 || rrow[s] != 0)) sstartL[r++] = (unsigned short)s;
  }
  if (tid == 0) { sstartL[total] = (unsigned short)steps; rowcnt[b] = total; }
  __syncthreads();

  const unsigned carry0 = (rrow[0] == 0) ? 1u : 0u;
  for (unsigned rr = tid; rr < total; rr += 256) {
    int st = sstartL[rr];
    int len = (int)sstartL[rr + 1] - st;
    unsigned carry = (st == 0) ? carry0 : 0u;
    unsigned rk = atomicAdd(&lcur[len], 1u);   // LDS; placement-only
    rowsegs[(size_t)b * T_DIM + rr] =
        (unsigned)st | ((unsigned)len << 10) | (rk << 21) | (carry << 31);
  }
  __syncthreads();
  for (int l = tid; l <= steps; l += 256) lhist[(size_t)l * 128 + b] = lcur[l];
}

// cursors[len] = #segs with len' > len; Warr[len] = work of len' > len; nseg.
__global__ __launch_bounds__(1024) void seg_prefix2(
    const unsigned* __restrict__ lhist, unsigned* __restrict__ rowoff,
    unsigned* __restrict__ cursors, unsigned* __restrict__ Warr,
    unsigned* __restrict__ nseg, int steps) {
  __shared__ unsigned cs[1024];
  __shared__ unsigned cs2[1024];
  const int tid = threadIdx.x;
  const int len = tid + 1;
  unsigned run = 0;
  if (len <= steps) {
    for (int b = 0; b < 128; ++b) {
      rowoff[(size_t)len * 128 + b] = run;
      run += lhist[(size_t)len * 128 + b];
    }
  }
  unsigned own = run;
  unsigned own2 = run * (unsigned)len;
  cs[tid] = own;
  cs2[tid] = own2;
  for (int off = 1; off < 1024; off <<= 1) {
    __syncthreads();
    unsigned v = (tid + off < 1024) ? cs[tid + off] : 0u;
    unsigned v2 = (tid + off < 1024) ? cs2[tid + off] : 0u;
    __syncthreads();
    cs[tid] += v;
    cs2[tid] += v2;
  }
  cursors[len] = cs[tid] - own;
  Warr[len] = cs2[tid] - own2;
  if (tid == 0) *nseg = cs[0];
}

// segs: start(10) | len(11)<<10 | b(7)<<21 | carry(1)<<28  (length-sorted desc)
__global__ void seg_scatter2(
    const unsigned* __restrict__ rowsegs, const unsigned* __restrict__ rowcnt,
    const unsigned* __restrict__ rowoff, const unsigned* __restrict__ cursors,
    unsigned* __restrict__ segs) {
  int i = blockIdx.x * 256 + threadIdx.x;
  int b = i >> 10;
  int rr = i & 1023;
  if ((unsigned)rr >= rowcnt[b]) return;
  unsigned rec = rowsegs[i];
  unsigned st = rec & 0x3FF;
  unsigned len = (rec >> 10) & 0x7FF;
  unsigned rk = (rec >> 21) & 0x3FF;
  unsigned carry = rec >> 31;
  unsigned dst = cursors[len] + rowoff[(size_t)len * 128 + b] + rk;
  segs[dst] = st | (len << 10) | ((unsigned)b << 21) | (carry << 28);
}

// Stream boundary marks via closed-form preex. sstart/preexS pre-memset 0xFF.
__global__ void str_mark(
    const unsigned* __restrict__ segs, const unsigned* __restrict__ nseg_p,
    const unsigned* __restrict__ cursors, const unsigned* __restrict__ Warr,
    unsigned* __restrict__ sstart, unsigned* __restrict__ preexS, int Q) {
  unsigned r = blockIdx.x * 256 + threadIdx.x;
  unsigned n = *nseg_p;
  if (r >= n) return;
  unsigned rec = segs[r];
  unsigned len = (rec >> 10) & 0x7FF;
  unsigned pre = Warr[len] + len * (r - cursors[len]);
  unsigned st = pre / (unsigned)Q;
  unsigned stp;
  if (r == 0) {
    sstart[0] = 0; preexS[0] = 0; stp = 0;
  } else {
    unsigned rec2 = segs[r - 1];
    unsigned len2 = (rec2 >> 10) & 0x7FF;
    unsigned pre2 = Warr[len2] + len2 * (r - 1 - cursors[len2]);
    stp = pre2 / (unsigned)Q;
  }
  for (unsigned s = stp + 1; s <= st; ++s) { sstart[s] = r; preexS[s] = pre; }
}

// ---------------- phase 1: gi GEMM (f32 A, dbuf + counted vmcnt) ----------------
// A: ins slice [M][256] f32. BT: WiTp [768][256] f16. Flat grid 6*(M/128),
// XCD-swizzled (verified R10: FETCH = A size). T3 2-phase: stage k+1 before
// computing k; vmcnt(6) = wait the older batch while 6 newer ride. Last iter
// stages a dummy wrapped tile (keeps count constant; buffer never read).
__global__ __launch_bounds__(256) void gi_gemm(
    const float* __restrict__ A,
    const _Float16* __restrict__ BT,
    const float* __restrict__ bip,
    _Float16* __restrict__ Cout,
    int M) {
  __shared__ float    Af[2][128 * 32];     // 32 KB (f32 A tiles)
  __shared__ _Float16 Bl[2][128 * 32];     // 16 KB
  const int tid = threadIdx.x;
  const int lane = tid & 63;
  const int w = tid >> 6;
  const int wr = w >> 1, wc = w & 1;

  const int bid = blockIdx.x;
  const int nwg = gridDim.x;            // 6*(M/128), divisible by 8
  const int swz = (bid & 7) * (nwg >> 3) + (bid >> 3);
  const int bx = swz % 6;
  const int by = swz / 6;
  const int m0 = by * 128;
  const int n0 = bx * 128;

  const int srowA = lane >> 3;          // 0..7
  const int scolA = ((lane & 7) * 16) ^ (srowA << 4);
  const int srowB = lane >> 2;          // 0..15
  const int scolB = ((lane & 3) * 16) ^ ((srowB & 3) << 4);

  auto STAGE = [&](int buf, int ks) {
#pragma unroll
    for (int g = 0; g < 4; ++g) {
      const int rowA = w * 32 + g * 8;   // wave-uniform
      __builtin_amdgcn_global_load_lds(
          (const __attribute__((address_space(1))) void*)
              ((const char*)A + ((size_t)(m0 + rowA + srowA) * 256 + ks) * 4 + scolA),
          (__attribute__((address_space(3))) void*)((char*)Af[buf] + rowA * 128),
          16, 0, 0);
    }
#pragma unroll
    for (int g = 0; g < 2; ++g) {
      const int rowB = w * 32 + g * 16;  // wave-uniform
      __builtin_amdgcn_global_load_lds(
          (const __attribute__((address_space(1))) void*)
              ((const char*)BT + ((size_t)(n0 + rowB + srowB) * 256 + ks) * 2 + scolB),
          (__attribute__((address_space(3))) void*)((char*)Bl[buf] + rowB * 64),
          16, 0, 0);
    }
  };

  f32x4 acc[4][4] = {};

  STAGE(0, 0);   // prologue: 6 loads in flight

  int cur = 0;
  for (int ks = 0; ks < 256; ks += 32) {
    const int ksn = (ks + 32) & 255;     // last iter wraps -> dummy stage
    STAGE(cur ^ 1, ksn);                 // issue next tile (6 newer loads)

    // wait CURRENT tile's 6 loads (issued one iteration ago); 6 newest ride
    asm volatile("s_waitcnt vmcnt(6)" ::: "memory");
    __builtin_amdgcn_s_barrier();
    __builtin_amdgcn_sched_barrier(0);

    half8_t af[4], bf[4];
    const int swzA = (lane & 7) << 4;
#pragma unroll
    for (int m = 0; m < 4; ++m) {
      const int r = wr * 64 + m * 16 + (lane & 15);       // r&7 == lane&7
      const char* rowbase = (const char*)Af[cur] + (size_t)r * 128;
      const int cb = (lane >> 4) * 32;
      float4 a0 = *(const float4*)(rowbase + ((cb) ^ swzA));
      float4 a1 = *(const float4*)(rowbase + ((cb + 16) ^ swzA));
      half8_t h;
      h[0] = (_Float16)a0.x; h[1] = (_Float16)a0.y;
      h[2] = (_Float16)a0.z; h[3] = (_Float16)a0.w;
      h[4] = (_Float16)a1.x; h[5] = (_Float16)a1.y;
      h[6] = (_Float16)a1.z; h[7] = (_Float16)a1.w;
      af[m] = h;
    }
    const int swzB = (lane & 3) << 4;
#pragma unroll
    for (int n = 0; n < 4; ++n) {
      const int r = wc * 64 + n * 16 + (lane & 15);       // r&3 == lane&3
      const char* rowbase = (const char*)Bl[cur] + (size_t)r * 64;
      bf[n] = *(const half8_t*)(rowbase + (((lane >> 4) * 16) ^ swzB));
    }
#pragma unroll
    for (int m = 0; m < 4; ++m)
#pragma unroll
      for (int n = 0; n < 4; ++n)
        acc[m][n] = __builtin_amdgcn_mfma_f32_16x16x32_f16(af[m], bf[n], acc[m][n], 0, 0, 0);

    // reads of buf[cur] done before it is re-staged next iteration
    asm volatile("s_waitcnt lgkmcnt(0)" ::: "memory");
    __builtin_amdgcn_s_barrier();
    __builtin_amdgcn_sched_barrier(0);
    cur ^= 1;
  }

#pragma unroll
  for (int m = 0; m < 4; ++m) {
    int row = m0 + wr * 64 + m * 16 + (lane >> 4) * 4;
#pragma unroll
    for (int n = 0; n < 4; ++n) {
      int col = n0 + wc * 64 + n * 16 + (lane & 15);
      float bv = bip[col];
#pragma unroll
      for (int r2 = 0; r2 < 4; ++r2)
        Cout[(size_t)(row + r2) * N3 + col] = (_Float16)(acc[m][n][r2] + bv);
    }
  }
}

// ---------------- phase 2: stream-packed scan, v13 (= v8 + rcp math) ----------------
// rcur/rnxt record: t(10) | b(7)<<10 | rem(11)<<17 | carry(1)<<28
__global__ __launch_bounds__(512)
__attribute__((amdgpu_waves_per_eu(1, 2)))
void scan_stream(
    const _Float16* __restrict__ WhB,
    const _Float16* __restrict__ gi,
    const unsigned* __restrict__ segs,
    const unsigned* __restrict__ sstart,
    const unsigned* __restrict__ preexS,
    const unsigned* __restrict__ nseg_ptr,
    const float* __restrict__ bhn,
    const float* __restrict__ h_in,
    float* __restrict__ h_out,
    float* __restrict__ ys,
    float* __restrict__ hfin,
    float* __restrict__ dump,
    int t0, int steps, int Q) {
  __shared__ _Float16 h_lds[2][ROWS][264];   // 16.9 KB (double-buffered)
  __shared__ _Float16 giL[2][ROWS][776];     // 49.7 KB (double-buffered)
  __shared__ unsigned rst[ROWS];             // setup-only seeding
  __shared__ unsigned rowrankL[ROWS];
  __shared__ unsigned rowpwL[ROWS];
  __shared__ unsigned wava[8];

  const int tid = threadIdx.x;
  const int lane = tid & 63;
  const int w = tid >> 6;
  const int sbase = blockIdx.x * ROWS;
  const unsigned nseg = *nseg_ptr;
  float* dumpb = dump + (size_t)(blockIdx.x & 63) * 4096;

  // ---- row init from stream marks ----
  if (tid < ROWS) {
    const unsigned st = sbase + tid;
    unsigned r = sstart[st], pw = preexS[st];
    unsigned v = 0u, rk = 0xFFFFFFFFu, rpw0 = 0u;
    if (r < nseg && pw < (st + 1) * (unsigned)Q) {
      unsigned rec = segs[r];
      unsigned len = (rec >> 10) & 0x7FF;
      v = (rec & 0x3FF) | (((rec >> 21) & 0x7F) << 10) | (len << 17) |
          (((rec >> 28) & 1u) << 28);
      rk = r; rpw0 = pw + len;
    }
    rst[tid] = v; rowrankL[tid] = rk; rowpwL[tid] = rpw0;
  }
  if (tid < 8) wava[tid] = 1u;

  // ---- resident Wh: 48 B-fragments (192 regs), loaded once ----
  half8_t whr[48];
#pragma unroll
  for (int kt = 0; kt < 8; ++kt)
#pragma unroll
    for (int q = 0; q < 6; ++q)
      whr[kt * 6 + q] =
          *(const half8_t*)&WhB[(((size_t)kt * 48 + w * 6 + q) * 64 + lane) * 8];

  __syncthreads();

  // ---- per-wave register state for owned rows 2w, 2w+1 ----
  unsigned rcur[2], rnxt[2], rrk[2], rpw[2], segnx[2], lim[2];
  unsigned rfr[2];
#pragma unroll
  for (int rr = 0; rr < 2; ++rr) {
    const int row = 2 * w + rr;
    rcur[rr] = rst[row];
    rrk[rr]  = rowrankL[row];
    rpw[rr]  = rowpwL[row];
    lim[rr]  = (unsigned)(sbase + row + 1) * (unsigned)Q;
    unsigned rn2 = rrk[rr] + 1;
    unsigned i2 = (rn2 < nseg) ? rn2 : (nseg - 1);
    segnx[rr] = segs[i2];
  }

  // initial h into h_lds[0]
#pragma unroll
  for (int rr = 0; rr < 2; ++rr) {
    int row = 2 * w + rr;
    unsigned s = rcur[rr];
    float4 o = make_float4(0.f, 0.f, 0.f, 0.f);
    if (s & (1u << 28))
      o = *(const float4*)&h_in[(size_t)((s >> 10) & 0x7F) * 256 + lane * 4];
    half4_t hv;
    hv.x = (_Float16)o.x; hv.y = (_Float16)o.y;
    hv.z = (_Float16)o.z; hv.w = (_Float16)o.w;
    *(half4_t*)&h_lds[0][row][lane * 4] = hv;
  }

  // ---- prologue DMA: gi for step 0 into giL[0] (constant 6 loads) ----
#pragma unroll
  for (int rr = 0; rr < 2; ++rr) {
    const int row = 2 * w + rr;
    const unsigned ss = rcur[rr];
    const int live = (int)((ss >> 17) & 0x7FF);
    const size_t goff = live ? ((size_t)(ss & 0x3FF) * B_DIM + ((ss >> 10) & 0x7F)) * N3 : 0;
    const char* src = (const char*)(gi + goff);
    char* dst = (char*)&giL[0][row][0];
    __builtin_amdgcn_global_load_lds(
        (const __attribute__((address_space(1))) void*)(src + (size_t)lane * 16),
        (__attribute__((address_space(3))) void*)dst, 16, 0, 0);
    __builtin_amdgcn_global_load_lds(
        (const __attribute__((address_space(1))) void*)(src + 1024 + (size_t)lane * 4),
        (__attribute__((address_space(3))) void*)(dst + 1024), 4, 0, 0);
    __builtin_amdgcn_global_load_lds(
        (const __attribute__((address_space(1))) void*)(src + 1280 + (size_t)lane * 4),
        (__attribute__((address_space(3))) void*)(dst + 1280), 4, 0, 0);
  }
  // prologue dummy stores: establish the constant [6 loads][2 stores] tail
#pragma unroll
  for (int rr = 0; rr < 2; ++rr) {
    const int row = 2 * w + rr;
    *(float4*)&dumpb[row * 256 + lane * 4] = make_float4(0.f, 0.f, 0.f, 0.f);
  }

  const int r16 = lane & 15;
  const int q4 = (lane >> 4) * 4;
  const int kq8 = (lane >> 4) * 8;
  const int u0 = w * 32 + r16;
  const float bh0 = bhn[u0];
  const float bh1 = bhn[u0 + 16];

  int cur = 0;   // giL buffer holding CURRENT step's gi
  int hc = 0;    // h buffer holding CURRENT step's input h
  while (true) {
    // ==== (C): counted wait. Per-wave VMEM tail is [6 gload_lds][2 stores]
    // (+rare conditional stores, all NEWER than the loads) -> vmcnt(2)
    // guarantees all 6 loads done; the 2 newest stores retire under the
    // next iteration's compute (T4: never drain to 0 in the loop).
    asm volatile("s_waitcnt vmcnt(2)" ::: "memory");
    asm volatile("s_waitcnt lgkmcnt(0)" ::: "memory");
    __builtin_amdgcn_s_barrier();
    __builtin_amdgcn_sched_barrier(0);

    unsigned alive = 0;
#pragma unroll
    for (int i = 0; i < 8; ++i) alive += wava[i];
    if (!alive) break;

    // ---- roll-early: compute next-step state (wave-uniform, registers) ----
#pragma unroll
    for (int rr = 0; rr < 2; ++rr) {
      const unsigned cs = rcur[rr];
      const unsigned rem = (cs >> 17) & 0x7FF;
      unsigned nx = 0u;
      rfr[rr] = 0u;
      if (rem > 1) {
        nx = ((cs & 0x3FF) + 1) | (cs & (0x7Fu << 10)) | ((rem - 1) << 17);
      } else if (rem == 1) {
        unsigned rn = rrk[rr] + 1;
        unsigned pw = rpw[rr];
        if (rn < nseg && pw < lim[rr]) {
          unsigned rec = segnx[rr];
          unsigned len = (rec >> 10) & 0x7FF;
          nx = (rec & 0x3FF) | (((rec >> 21) & 0x7F) << 10) | (len << 17) |
               (((rec >> 28) & 1u) << 28);
          rrk[rr] = rn; rpw[rr] = pw + len;
          rfr[rr] = 1u;
          unsigned rn2 = rn + 1;
          unsigned i2 = (rn2 < nseg) ? rn2 : (nseg - 1);
          segnx[rr] = segs[i2];   // consumed >=1 iteration later
        }
      }
      rnxt[rr] = nx;
    }

    // ---- prefetch gi for NEXT step into giL[cur^1] (constant 6 loads) ----
#pragma unroll
    for (int rr = 0; rr < 2; ++rr) {
      const int row = 2 * w + rr;
      const unsigned ss = rnxt[rr];
      const int live = (int)((ss >> 17) & 0x7FF);
      const size_t goff = live ? ((size_t)(ss & 0x3FF) * B_DIM + ((ss >> 10) & 0x7F)) * N3 : 0;
      const char* src = (const char*)(gi + goff);
      char* dst = (char*)&giL[cur ^ 1][row][0];
      __builtin_amdgcn_global_load_lds(
          (const __attribute__((address_space(1))) void*)(src + (size_t)lane * 16),
          (__attribute__((address_space(3))) void*)dst, 16, 0, 0);
      __builtin_amdgcn_global_load_lds(
          (const __attribute__((address_space(1))) void*)(src + 1024 + (size_t)lane * 4),
          (__attribute__((address_space(3))) void*)(dst + 1024), 4, 0, 0);
      __builtin_amdgcn_global_load_lds(
          (const __attribute__((address_space(1))) void*)(src + 1280 + (size_t)lane * 4),
          (__attribute__((address_space(3))) void*)(dst + 1280), 4, 0, 0);
    }

    // ---- MFMA: gh(16 rows) = h @ Wh, A from h_lds[hc], B from registers ----
    f32x4 acc[6] = {};
#pragma unroll
    for (int kt = 0; kt < 8; ++kt) {
      half8_t afr = *(const half8_t*)&h_lds[hc][r16][kt * 32 + kq8];
#pragma unroll
      for (int q = 0; q < 6; ++q)
        acc[q] = __builtin_amdgcn_mfma_f32_16x16x32_f16(afr, whr[kt * 6 + q], acc[q], 0, 0, 0);
    }

    // ---- gates: UNCONDITIONAL, inline loads (v8 form), rcp math (v13).
    // Dead rows produce confined garbage; consumers stay liveness-guarded. ----
#pragma unroll
    for (int j = 0; j < 2; ++j) {
      const int u = u0 + j * 16;
      const int cb = w * 96 + j * 48 + r16;
      const float bh = j ? bh1 : bh0;
#pragma unroll
      for (int e = 0; e < 4; ++e) {
        const int row = q4 + e;
        const float gr = (float)giL[cur][row][cb];
        const float gz = (float)giL[cur][row][cb + 16];
        const float gn = (float)giL[cur][row][cb + 32];
        const float sigr = __builtin_amdgcn_rcpf(1.f + __expf(-(gr + acc[3 * j][e])));
        const float sigz = __builtin_amdgcn_rcpf(1.f + __expf(-(gz + acc[3 * j + 1][e])));
        const float narg = fmaf(sigr, acc[3 * j + 2][e] + bh, gn);
        const float eo = __expf(-2.f * narg);
        const float nn = fmaf(2.f, __builtin_amdgcn_rcpf(1.f + eo), -1.f);
        const float hold = (float)h_lds[hc][row][u];
        const float hnew = fmaf(sigz, hold - nn, nn);
        h_lds[hc ^ 1][row][u] = (_Float16)hnew;
      }
    }

    // ==== (G2): gate ds_writes drained -> full h[hc^1] rows readable.
    asm volatile("s_waitcnt lgkmcnt(0)" ::: "memory");
    __builtin_amdgcn_s_barrier();
    __builtin_amdgcn_sched_barrier(0);

    // ---- output (constant 2 stores) + state + fresh h init (wave-local) ----
    unsigned alv = 0;
#pragma unroll
    for (int rr = 0; rr < 2; ++rr) {
      const int row = 2 * w + rr;
      const unsigned sp = rcur[rr];
      const unsigned rem = (sp >> 17) & 0x7FF;
      const int t = sp & 0x3FF;
      const int b = (sp >> 10) & 0x7F;
      half4_t hv = *(const half4_t*)&h_lds[hc ^ 1][row][lane * 4];
      float4 o;
      o.x = (float)hv.x; o.y = (float)hv.y; o.z = (float)hv.z; o.w = (float)hv.w;
      float* ydst = rem
          ? &ys[(((size_t)(t0 + t) * B_DIM + b) * H_DIM) + lane * 4]
          : &dumpb[row * 256 + lane * 4];
      *(float4*)ydst = o;
      if (rem == 1) {
        if (t == steps - 1) *(float4*)&h_out[(size_t)b * 256 + lane * 4] = o;
        if (t0 + t == T_DIM - 1) *(float4*)&hfin[(size_t)b * 256 + lane * 4] = o;
      }
      if ((rnxt[rr] >> 17) & 0x7FF) alv++;
      rcur[rr] = rnxt[rr];
      // fresh-segment h init into h[hc^1] (own rows; after output read above)
      if (rfr[rr]) {
        unsigned s = rnxt[rr];
        float4 o2 = make_float4(0.f, 0.f, 0.f, 0.f);
        if (s & (1u << 28))
          o2 = *(const float4*)&h_in[(size_t)((s >> 10) & 0x7F) * 256 + lane * 4];
        half4_t hv2;
        hv2.x = (_Float16)o2.x; hv2.y = (_Float16)o2.y;
        hv2.z = (_Float16)o2.z; hv2.w = (_Float16)o2.w;
        *(half4_t*)&h_lds[hc ^ 1][row][lane * 4] = hv2;
      }
    }
    if (lane == 0) wava[w] = alv;

    cur ^= 1;
    hc ^= 1;
  }
}

// ---------------- launch ----------------
extern "C" void kernel_launch(void* const* d_in, const int* in_sizes, int n_in,
                              void* d_out, int out_size, void* d_ws, size_t ws_size,
                              hipStream_t stream) {
  const float* ins    = (const float*)d_in[0];
  const int*   resets = (const int*)d_in[1];
  const float* h0     = (const float*)d_in[2];
  const float* Wi     = (const float*)d_in[3];
  const float* Wh     = (const float*)d_in[4];
  const float* bi     = (const float*)d_in[5];
  const float* bhn    = (const float*)d_in[6];
  float* out  = (float*)d_out;
  float* hfin = out;
  float* ys   = out + B_DIM * H_DIM;

  char* ws = (char*)d_ws;
  unsigned*  WhB     = (unsigned*)(ws + 0);            //  393216
  _Float16*  WiTp    = (_Float16*)(ws + 393216);       //  393216 -> 786432
  float*     bip     = (float*)(ws + 786432);          //    3072 -> 789504
  float*     hA      = (float*)(ws + 789504);          //  131072 -> 920576
  float*     hB      = (float*)(ws + 920576);          //  131072 -> 1051648
  int*       resT    = (int*)(ws + 1051648);           //  524288 -> 1575936
  unsigned*  rowsegs = (unsigned*)(ws + 1575936);      //  524288 -> 2100224
  unsigned*  rowcnt  = (unsigned*)(ws + 2100224);      //     512 -> 2100736
  unsigned*  lhist   = (unsigned*)(ws + 2100736);      //  524800 -> 2625536
  unsigned*  rowoff  = (unsigned*)(ws + 2625536);      //  524800 -> 3150336
  unsigned*  cursors = (unsigned*)(ws + 3150336);      //    4100 -> 3154560 (pad)
  unsigned*  Warr    = (unsigned*)(ws + 3154560);      //    4100 -> 3158784 (pad)
  unsigned*  nseg    = (unsigned*)(ws + 3158784);      //       4 -> 3158912 (pad)
  unsigned*  segs    = (unsigned*)(ws + 3158912);      //  524288 -> 3683200
  unsigned*  sstart  = (unsigned*)(ws + 3683200);      //   65536 -> 3748736
  unsigned*  preexS  = (unsigned*)(ws + 3748736);      //   65536 -> 3814272
  float*     dump    = (float*)(ws + 3814400);         // 1048576 -> 4862976
  const size_t gi_off = 4862976;                       // 256B aligned

  // gi (CH*128*768 f16) after gi_off
  int CH = T_DIM;
  while (CH > 256) {
    size_t need = gi_off + (size_t)CH * 128 * N3 * 2;
    if (need <= ws_size) break;
    CH >>= 1;
  }
  _Float16* gibuf = (_Float16*)(ws + gi_off);

  prep_whb<<<384, 256, 0, stream>>>(Wh, WhB);
  prep_witp<<<768, 256, 0, stream>>>(Wi, WiTp);
  prep_bip<<<1, 768, 0, stream>>>(bi, bip);
  init_h<<<128, 256, 0, stream>>>(h0, hA);
  seg_transpose<<<512, 256, 0, stream>>>(resets, resT);

  float* hbufs[2] = {hA, hB};
  for (int c = 0, t0 = 0; t0 < T_DIM; ++c, t0 += CH) {
    int steps = (t0 + CH <= T_DIM) ? CH : (T_DIM - t0);
    int M = steps * B_DIM;
    int Q = (M + NSTREAM - 1) / NSTREAM;   // equal-work quantum (32 @ CH=1024)
    if (Q < 1) Q = 1;

    gi_gemm<<<6 * (M / 128), 256, 0, stream>>>(
        ins + (size_t)t0 * B_DIM * H_DIM, WiTp, bip, gibuf, M);

    seg_extract<<<128, 256, 0, stream>>>(resT, t0, steps, rowsegs, rowcnt, lhist);
    seg_prefix2<<<1, 1024, 0, stream>>>(lhist, rowoff, cursors, Warr, nseg, steps);
    seg_scatter2<<<512, 256, 0, stream>>>(rowsegs, rowcnt, rowoff, cursors, segs);
    hipMemsetAsync(sstart, 0xFF, 131072, stream);   // sstart + preexS
    str_mark<<<512, 256, 0, stream>>>(segs, nseg, cursors, Warr, sstart, preexS, Q);

    scan_stream<<<NSTREAM / ROWS, 512, 0, stream>>>(
        (const _Float16*)WhB, gibuf, segs, sstart, preexS, nseg, bhn,
        hbufs[c & 1], hbufs[(c + 1) & 1], ys, hfin, dump, t0, steps, Q);
  }
}

// Round 13
// 371.992 us; speedup vs baseline: 1.0301x; 1.0301x over previous
//
#include <hip/hip_runtime.h>

// ScannedRNN (GRU w/ reset masking) T=1024,B=128,H=256 — stream-packed
// segment-parallel scan, v17: gemm LDS epilogue (256B-segment C writes) +
// seg_prefix2 batched loads. scan = v13 winner (180us).
//
//   R12 ledger: gemm dbuf NEUTRAL -> not staging-latency-bound. Re-derive:
//   C epilogue wrote 196MB as 2B scalar stores in 32B segments (half HBM
//   burst wasted ~ the inferred ~155us gemm). seg_prefix2 = 128-iter
//   loop-carried global-load chain on ONE CU (~35us serial).
//   v17: (1) epilogue: stage C tile in dead Af LDS (row-XOR swz), barrier,
//   write 16B chunks with 16 lanes = full 256B row (coalesced). Dummy wrap
//   stage removed (last iter vmcnt(0)) so LDS reuse is race-free.
//   (2) seg_prefix2: 8 batches x 4 uint4 independent loads, reg accumulate,
//   uint4 stores.
//
// Column permutation: c' = 48*(u>>4) + g*16 + (u&15), g in {r,z,n}. Wave w
// owns c' [96w,96w+96) = u in [32w,32w+32) with complete gate triples.

typedef _Float16 half2_t __attribute__((ext_vector_type(2)));
typedef _Float16 half4_t __attribute__((ext_vector_type(4)));
typedef _Float16 half8_t __attribute__((ext_vector_type(8)));
typedef float f32x4 __attribute__((ext_vector_type(4)));

#define T_DIM 1024
#define B_DIM 128
#define H_DIM 256
#define N3 768
#define NSTREAM 4096    // 256 blocks x 16 rows
#define ROWS 16

__device__ __forceinline__ int perm_n(int cp) {
  int ublk = cp / 48;
  int rem = cp % 48;
  int g = rem >> 4;
  int u4 = rem & 15;
  return g * 256 + ublk * 16 + u4;
}

// ---------------- prepack ----------------

__global__ void prep_whb(const float* __restrict__ Wh, unsigned* __restrict__ WhB) {
  int i = blockIdx.x * 256 + threadIdx.x;   // 0..98303 (dword = 2 halves)
  int h = 2 * i;
  int idx = h & 7;
  int lane = (h >> 3) & 63;
  int ntk = h >> 9;
  int nt = ntk % 48;
  int kt = ntk / 48;
  int k = kt * 32 + ((lane >> 4) * 8) + idx;
  int n = perm_n(nt * 16 + (lane & 15));
  half2_t p;
  p.x = (_Float16)Wh[(size_t)k * N3 + n];
  p.y = (_Float16)Wh[(size_t)(k + 1) * N3 + n];
  WhB[i] = __builtin_bit_cast(unsigned, p);
}

__global__ void prep_witp(const float* __restrict__ Wi, _Float16* __restrict__ WiTp) {
  int i = blockIdx.x * 256 + threadIdx.x;   // 0..196607
  int cp = i >> 8;
  int k = i & 255;
  WiTp[(size_t)cp * 256 + k] = (_Float16)Wi[(size_t)k * N3 + perm_n(cp)];
}

__global__ void prep_bip(const float* __restrict__ bi, float* __restrict__ bip) {
  int i = threadIdx.x;
  bip[i] = bi[perm_n(i)];
}

__global__ void init_h(const float* __restrict__ h0, float* __restrict__ h_state) {
  int i = blockIdx.x * 256 + threadIdx.x;
  h_state[i] = h0[i];
}

// ---------------- segment extraction ----------------

__global__ void seg_transpose(const int* __restrict__ resets, int* __restrict__ resT) {
  int i = blockIdx.x * 256 + threadIdx.x;   // 0..131071
  int b = i >> 10;
  int t = i & 1023;
  resT[i] = resets[(size_t)t * B_DIM + b];
}

// rec: start(10) | len(11)<<10 | rankInRowLen(10)<<21 | carry(1)<<31
__global__ __launch_bounds__(256) void seg_extract(
    const int* __restrict__ resT, int t0, int steps,
    unsigned* __restrict__ rowsegs, unsigned* __restrict__ rowcnt,
    unsigned* __restrict__ lhist) {
  const int b = blockIdx.x;
  const int tid = threadIdx.x;
  const int lane = tid & 63;
  const int w = tid >> 6;
  const int per = (steps + 255) >> 8;

  __shared__ unsigned short sstartL[1025];
  __shared__ unsigned lcur[1025];
  __shared__ unsigned wsum[4];

  for (int l = tid; l <= steps; l += 256) lcur[l] = 0;

  const int* rrow = resT + (size_t)b * T_DIM + t0;
  int myfirst = tid * per;
  unsigned cnt = 0;
  for (int i = 0; i < per; ++i) {
    int s = myfirst + i;
    if (s < steps && (s == 0 || rrow[s] != 0)) cnt++;
  }
  unsigned pre = cnt;
#pragma unroll
  for (int off = 1; off < 64; off <<= 1) {
    unsigned v = __shfl_up(pre, off);
    if (lane >= off) pre += v;
  }
  if (lane == 63) wsum[w] = pre;
  __syncthreads();
  unsigned wbase = 0, total = 0;
#pragma unroll
  for (int i = 0; i < 4; ++i) {
    if (i < w) wbase += wsum[i];
    total += wsum[i];
  }
  unsigned r = wbase + pre - cnt;
  for (int i = 0; i < per; ++i) {
    int s = myfirst + i;
    if (s < steps && (s == 0 || rrow[s] != 0)) sstartL[r++] = (unsigned short)s;
  }
  if (tid == 0) { sstartL[total] = (unsigned short)steps; rowcnt[b] = total; }
  __syncthreads();

  const unsigned carry0 = (rrow[0] == 0) ? 1u : 0u;
  for (unsigned rr = tid; rr < total; rr += 256) {
    int st = sstartL[rr];
    int len = (int)sstartL[rr + 1] - st;
    unsigned carry = (st == 0) ? carry0 : 0u;
    unsigned rk = atomicAdd(&lcur[len], 1u);   // LDS; placement-only
    rowsegs[(size_t)b * T_DIM + rr] =
        (unsigned)st | ((unsigned)len << 10) | (rk << 21) | (carry << 31);
  }
  __syncthreads();
  for (int l = tid; l <= steps; l += 256) lhist[(size_t)l * 128 + b] = lcur[l];
}

// cursors[len] = #segs with len' > len; Warr[len] = work of len' > len; nseg.
// v17: the 128-long loop-carried load chain is batched (4x uint4 independent
// loads per 16 values -> pipelined), rowoff stored as coalesced uint4.
__global__ __launch_bounds__(1024) void seg_prefix2(
    const unsigned* __restrict__ lhist, unsigned* __restrict__ rowoff,
    unsigned* __restrict__ cursors, unsigned* __restrict__ Warr,
    unsigned* __restrict__ nseg, int steps) {
  __shared__ unsigned cs[1024];
  __shared__ unsigned cs2[1024];
  const int tid = threadIdx.x;
  const int len = tid + 1;
  unsigned run = 0;
  if (len <= steps) {
    const uint4* src = (const uint4*)&lhist[(size_t)len * 128];
    uint4* dst = (uint4*)&rowoff[(size_t)len * 128];
#pragma unroll 1
    for (int bb = 0; bb < 8; ++bb) {
      uint4 v0 = src[bb * 4 + 0];
      uint4 v1 = src[bb * 4 + 1];
      uint4 v2 = src[bb * 4 + 2];
      uint4 v3 = src[bb * 4 + 3];
      uint4 r0, r1, r2, r3;
      r0.x = run; run += v0.x; r0.y = run; run += v0.y;
      r0.z = run; run += v0.z; r0.w = run; run += v0.w;
      r1.x = run; run += v1.x; r1.y = run; run += v1.y;
      r1.z = run; run += v1.z; r1.w = run; run += v1.w;
      r2.x = run; run += v2.x; r2.y = run; run += v2.y;
      r2.z = run; run += v2.z; r2.w = run; run += v2.w;
      r3.x = run; run += v3.x; r3.y = run; run += v3.y;
      r3.z = run; run += v3.z; r3.w = run; run += v3.w;
      dst[bb * 4 + 0] = r0;
      dst[bb * 4 + 1] = r1;
      dst[bb * 4 + 2] = r2;
      dst[bb * 4 + 3] = r3;
    }
  }
  unsigned own = run;
  unsigned own2 = run * (unsigned)len;
  cs[tid] = own;
  cs2[tid] = own2;
  for (int off = 1; off < 1024; off <<= 1) {
    __syncthreads();
    unsigned v = (tid + off < 1024) ? cs[tid + off] : 0u;
    unsigned v2 = (tid + off < 1024) ? cs2[tid + off] : 0u;
    __syncthreads();
    cs[tid] += v;
    cs2[tid] += v2;
  }
  cursors[len] = cs[tid] - own;
  Warr[len] = cs2[tid] - own2;
  if (tid == 0) *nseg = cs[0];
}

// segs: start(10) | len(11)<<10 | b(7)<<21 | carry(1)<<28  (length-sorted desc)
__global__ void seg_scatter2(
    const unsigned* __restrict__ rowsegs, const unsigned* __restrict__ rowcnt,
    const unsigned* __restrict__ rowoff, const unsigned* __restrict__ cursors,
    unsigned* __restrict__ segs) {
  int i = blockIdx.x * 256 + threadIdx.x;
  int b = i >> 10;
  int rr = i & 1023;
  if ((unsigned)rr >= rowcnt[b]) return;
  unsigned rec = rowsegs[i];
  unsigned st = rec & 0x3FF;
  unsigned len = (rec >> 10) & 0x7FF;
  unsigned rk = (rec >> 21) & 0x3FF;
  unsigned carry = rec >> 31;
  unsigned dst = cursors[len] + rowoff[(size_t)len * 128 + b] + rk;
  segs[dst] = st | (len << 10) | ((unsigned)b << 21) | (carry << 28);
}

// Stream boundary marks via closed-form preex. sstart/preexS pre-memset 0xFF.
__global__ void str_mark(
    const unsigned* __restrict__ segs, const unsigned* __restrict__ nseg_p,
    const unsigned* __restrict__ cursors, const unsigned* __restrict__ Warr,
    unsigned* __restrict__ sstart, unsigned* __restrict__ preexS, int Q) {
  unsigned r = blockIdx.x * 256 + threadIdx.x;
  unsigned n = *nseg_p;
  if (r >= n) return;
  unsigned rec = segs[r];
  unsigned len = (rec >> 10) & 0x7FF;
  unsigned pre = Warr[len] + len * (r - cursors[len]);
  unsigned st = pre / (unsigned)Q;
  unsigned stp;
  if (r == 0) {
    sstart[0] = 0; preexS[0] = 0; stp = 0;
  } else {
    unsigned rec2 = segs[r - 1];
    unsigned len2 = (rec2 >> 10) & 0x7FF;
    unsigned pre2 = Warr[len2] + len2 * (r - 1 - cursors[len2]);
    stp = pre2 / (unsigned)Q;
  }
  for (unsigned s = stp + 1; s <= st; ++s) { sstart[s] = r; preexS[s] = pre; }
}

// ---------------- phase 1: gi GEMM (f32 A, dbuf, LDS epilogue) ----------------
// A: ins slice [M][256] f32. BT: WiTp [768][256] f16. Flat grid 6*(M/128),
// XCD-swizzled (verified R10: FETCH = A size). Dbuf: stage k+1 before
// computing k (vmcnt(6)); LAST iter waits vmcnt(0) (no dummy stage) so Af
// is reusable. Epilogue: C tile staged in Af (row-XOR swz), then 16 lanes
// write one full 256B row per inst (coalesced 256B segments vs old 32B).
__global__ __launch_bounds__(256) void gi_gemm(
    const float* __restrict__ A,
    const _Float16* __restrict__ BT,
    const float* __restrict__ bip,
    _Float16* __restrict__ Cout,
    int M) {
  __shared__ float    Af[2][128 * 32];     // 32 KB (f32 A tiles; C-staging after)
  __shared__ _Float16 Bl[2][128 * 32];     // 16 KB
  const int tid = threadIdx.x;
  const int lane = tid & 63;
  const int w = tid >> 6;
  const int wr = w >> 1, wc = w & 1;

  const int bid = blockIdx.x;
  const int nwg = gridDim.x;            // 6*(M/128), divisible by 8
  const int swz = (bid & 7) * (nwg >> 3) + (bid >> 3);
  const int bx = swz % 6;
  const int by = swz / 6;
  const int m0 = by * 128;
  const int n0 = bx * 128;

  const int srowA = lane >> 3;          // 0..7
  const int scolA = ((lane & 7) * 16) ^ (srowA << 4);
  const int srowB = lane >> 2;          // 0..15
  const int scolB = ((lane & 3) * 16) ^ ((srowB & 3) << 4);

  auto STAGE = [&](int buf, int ks) {
#pragma unroll
    for (int g = 0; g < 4; ++g) {
      const int rowA = w * 32 + g * 8;   // wave-uniform
      __builtin_amdgcn_global_load_lds(
          (const __attribute__((address_space(1))) void*)
              ((const char*)A + ((size_t)(m0 + rowA + srowA) * 256 + ks) * 4 + scolA),
          (__attribute__((address_space(3))) void*)((char*)Af[buf] + rowA * 128),
          16, 0, 0);
    }
#pragma unroll
    for (int g = 0; g < 2; ++g) {
      const int rowB = w * 32 + g * 16;  // wave-uniform
      __builtin_amdgcn_global_load_lds(
          (const __attribute__((address_space(1))) void*)
              ((const char*)BT + ((size_t)(n0 + rowB + srowB) * 256 + ks) * 2 + scolB),
          (__attribute__((address_space(3))) void*)((char*)Bl[buf] + rowB * 64),
          16, 0, 0);
    }
  };

  f32x4 acc[4][4] = {};

  STAGE(0, 0);   // prologue: 6 loads in flight

  int cur = 0;
  for (int ks = 0; ks < 256; ks += 32) {
    if (ks + 32 < 256) {
      STAGE(cur ^ 1, ks + 32);           // issue next tile (6 newer loads)
      asm volatile("s_waitcnt vmcnt(6)" ::: "memory");
    } else {
      asm volatile("s_waitcnt vmcnt(0)" ::: "memory");   // final: full drain
    }
    __builtin_amdgcn_s_barrier();
    __builtin_amdgcn_sched_barrier(0);

    half8_t af[4], bf[4];
    const int swzA = (lane & 7) << 4;
#pragma unroll
    for (int m = 0; m < 4; ++m) {
      const int r = wr * 64 + m * 16 + (lane & 15);       // r&7 == lane&7
      const char* rowbase = (const char*)Af[cur] + (size_t)r * 128;
      const int cb = (lane >> 4) * 32;
      float4 a0 = *(const float4*)(rowbase + ((cb) ^ swzA));
      float4 a1 = *(const float4*)(rowbase + ((cb + 16) ^ swzA));
      half8_t h;
      h[0] = (_Float16)a0.x; h[1] = (_Float16)a0.y;
      h[2] = (_Float16)a0.z; h[3] = (_Float16)a0.w;
      h[4] = (_Float16)a1.x; h[5] = (_Float16)a1.y;
      h[6] = (_Float16)a1.z; h[7] = (_Float16)a1.w;
      af[m] = h;
    }
    const int swzB = (lane & 3) << 4;
#pragma unroll
    for (int n = 0; n < 4; ++n) {
      const int r = wc * 64 + n * 16 + (lane & 15);       // r&3 == lane&3
      const char* rowbase = (const char*)Bl[cur] + (size_t)r * 64;
      bf[n] = *(const half8_t*)(rowbase + (((lane >> 4) * 16) ^ swzB));
    }
#pragma unroll
    for (int m = 0; m < 4; ++m)
#pragma unroll
      for (int n = 0; n < 4; ++n)
        acc[m][n] = __builtin_amdgcn_mfma_f32_16x16x32_f16(af[m], bf[n], acc[m][n], 0, 0, 0);

    // reads of buf[cur] done before it is re-staged next iteration
    asm volatile("s_waitcnt lgkmcnt(0)" ::: "memory");
    __builtin_amdgcn_s_barrier();
    __builtin_amdgcn_sched_barrier(0);
    cur ^= 1;
  }

  // ---- epilogue: stage C tile in LDS (row-XOR swz), coalesced row writes ----
  _Float16* CL = (_Float16*)Af;   // 32 KB = 128 rows x 256 B (Af is dead)
#pragma unroll
  for (int m = 0; m < 4; ++m) {
#pragma unroll
    for (int n = 0; n < 4; ++n) {
      const int col = wc * 64 + n * 16 + (lane & 15);
      const float bv = bip[n0 + col];
#pragma unroll
      for (int r2 = 0; r2 < 4; ++r2) {
        const int row = wr * 64 + m * 16 + (lane >> 4) * 4 + r2;
        const int boff = row * 256 + ((col * 2) ^ ((row & 7) << 4));
        *(_Float16*)((char*)CL + boff) = (_Float16)(acc[m][n][r2] + bv);
      }
    }
  }
  asm volatile("s_waitcnt lgkmcnt(0)" ::: "memory");
  __builtin_amdgcn_s_barrier();
  __builtin_amdgcn_sched_barrier(0);
  // wave w writes rows [32w,32w+32): per inst 4 rows x 256B (16 lanes/row)
#pragma unroll
  for (int k = 0; k < 8; ++k) {
    const int row = w * 32 + k * 4 + (lane >> 4);
    const int cb = (lane & 15) * 16;
    const char* src = (const char*)CL + row * 256 + (cb ^ ((row & 7) << 4));
    uint4 v = *(const uint4*)src;
    *(uint4*)((char*)Cout + ((size_t)(m0 + row) * N3 + n0) * 2 + cb) = v;
  }
}

// ---------------- phase 2: stream-packed scan, v13 (= v8 + rcp math) ----------------
// rcur/rnxt record: t(10) | b(7)<<10 | rem(11)<<17 | carry(1)<<28
__global__ __launch_bounds__(512)
__attribute__((amdgpu_waves_per_eu(1, 2)))
void scan_stream(
    const _Float16* __restrict__ WhB,
    const _Float16* __restrict__ gi,
    const unsigned* __restrict__ segs,
    const unsigned* __restrict__ sstart,
    const unsigned* __restrict__ preexS,
    const unsigned* __restrict__ nseg_ptr,
    const float* __restrict__ bhn,
    const float* __restrict__ h_in,
    float* __restrict__ h_out,
    float* __restrict__ ys,
    float* __restrict__ hfin,
    float* __restrict__ dump,
    int t0, int steps, int Q) {
  __shared__ _Float16 h_lds[2][ROWS][264];   // 16.9 KB (double-buffered)
  __shared__ _Float16 giL[2][ROWS][776];     // 49.7 KB (double-buffered)
  __shared__ unsigned rst[ROWS];             // setup-only seeding
  __shared__ unsigned rowrankL[ROWS];
  __shared__ unsigned rowpwL[ROWS];
  __shared__ unsigned wava[8];

  const int tid = threadIdx.x;
  const int lane = tid & 63;
  const int w = tid >> 6;
  const int sbase = blockIdx.x * ROWS;
  const unsigned nseg = *nseg_ptr;
  float* dumpb = dump + (size_t)(blockIdx.x & 63) * 4096;

  // ---- row init from stream marks ----
  if (tid < ROWS) {
    const unsigned st = sbase + tid;
    unsigned r = sstart[st], pw = preexS[st];
    unsigned v = 0u, rk = 0xFFFFFFFFu, rpw0 = 0u;
    if (r < nseg && pw < (st + 1) * (unsigned)Q) {
      unsigned rec = segs[r];
      unsigned len = (rec >> 10) & 0x7FF;
      v = (rec & 0x3FF) | (((rec >> 21) & 0x7F) << 10) | (len << 17) |
          (((rec >> 28) & 1u) << 28);
      rk = r; rpw0 = pw + len;
    }
    rst[tid] = v; rowrankL[tid] = rk; rowpwL[tid] = rpw0;
  }
  if (tid < 8) wava[tid] = 1u;

  // ---- resident Wh: 48 B-fragments (192 regs), loaded once ----
  half8_t whr[48];
#pragma unroll
  for (int kt = 0; kt < 8; ++kt)
#pragma unroll
    for (int q = 0; q < 6; ++q)
      whr[kt * 6 + q] =
          *(const half8_t*)&WhB[(((size_t)kt * 48 + w * 6 + q) * 64 + lane) * 8];

  __syncthreads();

  // ---- per-wave register state for owned rows 2w, 2w+1 ----
  unsigned rcur[2], rnxt[2], rrk[2], rpw[2], segnx[2], lim[2];
  unsigned rfr[2];
#pragma unroll
  for (int rr = 0; rr < 2; ++rr) {
    const int row = 2 * w + rr;
    rcur[rr] = rst[row];
    rrk[rr]  = rowrankL[row];
    rpw[rr]  = rowpwL[row];
    lim[rr]  = (unsigned)(sbase + row + 1) * (unsigned)Q;
    unsigned rn2 = rrk[rr] + 1;
    unsigned i2 = (rn2 < nseg) ? rn2 : (nseg - 1);
    segnx[rr] = segs[i2];
  }

  // initial h into h_lds[0]
#pragma unroll
  for (int rr = 0; rr < 2; ++rr) {
    int row = 2 * w + rr;
    unsigned s = rcur[rr];
    float4 o = make_float4(0.f, 0.f, 0.f, 0.f);
    if (s & (1u << 28))
      o = *(const float4*)&h_in[(size_t)((s >> 10) & 0x7F) * 256 + lane * 4];
    half4_t hv;
    hv.x = (_Float16)o.x; hv.y = (_Float16)o.y;
    hv.z = (_Float16)o.z; hv.w = (_Float16)o.w;
    *(half4_t*)&h_lds[0][row][lane * 4] = hv;
  }

  // ---- prologue DMA: gi for step 0 into giL[0] (constant 6 loads) ----
#pragma unroll
  for (int rr = 0; rr < 2; ++rr) {
    const int row = 2 * w + rr;
    const unsigned ss = rcur[rr];
    const int live = (int)((ss >> 17) & 0x7FF);
    const size_t goff = live ? ((size_t)(ss & 0x3FF) * B_DIM + ((ss >> 10) & 0x7F)) * N3 : 0;
    const char* src = (const char*)(gi + goff);
    char* dst = (char*)&giL[0][row][0];
    __builtin_amdgcn_global_load_lds(
        (const __attribute__((address_space(1))) void*)(src + (size_t)lane * 16),
        (__attribute__((address_space(3))) void*)dst, 16, 0, 0);
    __builtin_amdgcn_global_load_lds(
        (const __attribute__((address_space(1))) void*)(src + 1024 + (size_t)lane * 4),
        (__attribute__((address_space(3))) void*)(dst + 1024), 4, 0, 0);
    __builtin_amdgcn_global_load_lds(
        (const __attribute__((address_space(1))) void*)(src + 1280 + (size_t)lane * 4),
        (__attribute__((address_space(3))) void*)(dst + 1280), 4, 0, 0);
  }
  // prologue dummy stores: establish the constant [6 loads][2 stores] tail
#pragma unroll
  for (int rr = 0; rr < 2; ++rr) {
    const int row = 2 * w + rr;
    *(float4*)&dumpb[row * 256 + lane * 4] = make_float4(0.f, 0.f, 0.f, 0.f);
  }

  const int r16 = lane & 15;
  const int q4 = (lane >> 4) * 4;
  const int kq8 = (lane >> 4) * 8;
  const int u0 = w * 32 + r16;
  const float bh0 = bhn[u0];
  const float bh1 = bhn[u0 + 16];

  int cur = 0;   // giL buffer holding CURRENT step's gi
  int hc = 0;    // h buffer holding CURRENT step's input h
  while (true) {
    // ==== (C): counted wait. Per-wave VMEM tail is [6 gload_lds][2 stores]
    // (+rare conditional stores, all NEWER than the loads) -> vmcnt(2)
    // guarantees all 6 loads done; the 2 newest stores retire under the
    // next iteration's compute (T4: never drain to 0 in the loop).
    asm volatile("s_waitcnt vmcnt(2)" ::: "memory");
    asm volatile("s_waitcnt lgkmcnt(0)" ::: "memory");
    __builtin_amdgcn_s_barrier();
    __builtin_amdgcn_sched_barrier(0);

    unsigned alive = 0;
#pragma unroll
    for (int i = 0; i < 8; ++i) alive += wava[i];
    if (!alive) break;

    // ---- roll-early: compute next-step state (wave-uniform, registers) ----
#pragma unroll
    for (int rr = 0; rr < 2; ++rr) {
      const unsigned cs = rcur[rr];
      const unsigned rem = (cs >> 17) & 0x7FF;
      unsigned nx = 0u;
      rfr[rr] = 0u;
      if (rem > 1) {
        nx = ((cs & 0x3FF) + 1) | (cs & (0x7Fu << 10)) | ((rem - 1) << 17);
      } else if (rem == 1) {
        unsigned rn = rrk[rr] + 1;
        unsigned pw = rpw[rr];
        if (rn < nseg && pw < lim[rr]) {
          unsigned rec = segnx[rr];
          unsigned len = (rec >> 10) & 0x7FF;
          nx = (rec & 0x3FF) | (((rec >> 21) & 0x7F) << 10) | (len << 17) |
               (((rec >> 28) & 1u) << 28);
          rrk[rr] = rn; rpw[rr] = pw + len;
          rfr[rr] = 1u;
          unsigned rn2 = rn + 1;
          unsigned i2 = (rn2 < nseg) ? rn2 : (nseg - 1);
          segnx[rr] = segs[i2];   // consumed >=1 iteration later
        }
      }
      rnxt[rr] = nx;
    }

    // ---- prefetch gi for NEXT step into giL[cur^1] (constant 6 loads) ----
#pragma unroll
    for (int rr = 0; rr < 2; ++rr) {
      const int row = 2 * w + rr;
      const unsigned ss = rnxt[rr];
      const int live = (int)((ss >> 17) & 0x7FF);
      const size_t goff = live ? ((size_t)(ss & 0x3FF) * B_DIM + ((ss >> 10) & 0x7F)) * N3 : 0;
      const char* src = (const char*)(gi + goff);
      char* dst = (char*)&giL[cur ^ 1][row][0];
      __builtin_amdgcn_global_load_lds(
          (const __attribute__((address_space(1))) void*)(src + (size_t)lane * 16),
          (__attribute__((address_space(3))) void*)dst, 16, 0, 0);
      __builtin_amdgcn_global_load_lds(
          (const __attribute__((address_space(1))) void*)(src + 1024 + (size_t)lane * 4),
          (__attribute__((address_space(3))) void*)(dst + 1024), 4, 0, 0);
      __builtin_amdgcn_global_load_lds(
          (const __attribute__((address_space(1))) void*)(src + 1280 + (size_t)lane * 4),
          (__attribute__((address_space(3))) void*)(dst + 1280), 4, 0, 0);
    }

    // ---- MFMA: gh(16 rows) = h @ Wh, A from h_lds[hc], B from registers ----
    f32x4 acc[6] = {};
#pragma unroll
    for (int kt = 0; kt < 8; ++kt) {
      half8_t afr = *(const half8_t*)&h_lds[hc][r16][kt * 32 + kq8];
#pragma unroll
      for (int q = 0; q < 6; ++q)
        acc[q] = __builtin_amdgcn_mfma_f32_16x16x32_f16(afr, whr[kt * 6 + q], acc[q], 0, 0, 0);
    }

    // ---- gates: UNCONDITIONAL, inline loads (v8 form), rcp math (v13).
    // Dead rows produce confined garbage; consumers stay liveness-guarded. ----
#pragma unroll
    for (int j = 0; j < 2; ++j) {
      const int u = u0 + j * 16;
      const int cb = w * 96 + j * 48 + r16;
      const float bh = j ? bh1 : bh0;
#pragma unroll
      for (int e = 0; e < 4; ++e) {
        const int row = q4 + e;
        const float gr = (float)giL[cur][row][cb];
        const float gz = (float)giL[cur][row][cb + 16];
        const float gn = (float)giL[cur][row][cb + 32];
        const float sigr = __builtin_amdgcn_rcpf(1.f + __expf(-(gr + acc[3 * j][e])));
        const float sigz = __builtin_amdgcn_rcpf(1.f + __expf(-(gz + acc[3 * j + 1][e])));
        const float narg = fmaf(sigr, acc[3 * j + 2][e] + bh, gn);
        const float eo = __expf(-2.f * narg);
        const float nn = fmaf(2.f, __builtin_amdgcn_rcpf(1.f + eo), -1.f);
        const float hold = (float)h_lds[hc][row][u];
        const float hnew = fmaf(sigz, hold - nn, nn);
        h_lds[hc ^ 1][row][u] = (_Float16)hnew;
      }
    }

    // ==== (G2): gate ds_writes drained -> full h[hc^1] rows readable.
    asm volatile("s_waitcnt lgkmcnt(0)" ::: "memory");
    __builtin_amdgcn_s_barrier();
    __builtin_amdgcn_sched_barrier(0);

    // ---- output (constant 2 stores) + state + fresh h init (wave-local) ----
    unsigned alv = 0;
#pragma unroll
    for (int rr = 0; rr < 2; ++rr) {
      const int row = 2 * w + rr;
      const unsigned sp = rcur[rr];
      const unsigned rem = (sp >> 17) & 0x7FF;
      const int t = sp & 0x3FF;
      const int b = (sp >> 10) & 0x7F;
      half4_t hv = *(const half4_t*)&h_lds[hc ^ 1][row][lane * 4];
      float4 o;
      o.x = (float)hv.x; o.y = (float)hv.y; o.z = (float)hv.z; o.w = (float)hv.w;
      float* ydst = rem
          ? &ys[(((size_t)(t0 + t) * B_DIM + b) * H_DIM) + lane * 4]
          : &dumpb[row * 256 + lane * 4];
      *(float4*)ydst = o;
      if (rem == 1) {
        if (t == steps - 1) *(float4*)&h_out[(size_t)b * 256 + lane * 4] = o;
        if (t0 + t == T_DIM - 1) *(float4*)&hfin[(size_t)b * 256 + lane * 4] = o;
      }
      if ((rnxt[rr] >> 17) & 0x7FF) alv++;
      rcur[rr] = rnxt[rr];
      // fresh-segment h init into h[hc^1] (own rows; after output read above)
      if (rfr[rr]) {
        unsigned s = rnxt[rr];
        float4 o2 = make_float4(0.f, 0.f, 0.f, 0.f);
        if (s & (1u << 28))
          o2 = *(const float4*)&h_in[(size_t)((s >> 10) & 0x7F) * 256 + lane * 4];
        half4_t hv2;
        hv2.x = (_Float16)o2.x; hv2.y = (_Float16)o2.y;
        hv2.z = (_Float16)o2.z; hv2.w = (_Float16)o2.w;
        *(half4_t*)&h_lds[hc ^ 1][row][lane * 4] = hv2;
      }
    }
    if (lane == 0) wava[w] = alv;

    cur ^= 1;
    hc ^= 1;
  }
}

// ---------------- launch ----------------
extern "C" void kernel_launch(void* const* d_in, const int* in_sizes, int n_in,
                              void* d_out, int out_size, void* d_ws, size_t ws_size,
                              hipStream_t stream) {
  const float* ins    = (const float*)d_in[0];
  const int*   resets = (const int*)d_in[1];
  const float* h0     = (const float*)d_in[2];
  const float* Wi     = (const float*)d_in[3];
  const float* Wh     = (const float*)d_in[4];
  const float* bi     = (const float*)d_in[5];
  const float* bhn    = (const float*)d_in[6];
  float* out  = (float*)d_out;
  float* hfin = out;
  float* ys   = out + B_DIM * H_DIM;

  char* ws = (char*)d_ws;
  unsigned*  WhB     = (unsigned*)(ws + 0);            //  393216
  _Float16*  WiTp    = (_Float16*)(ws + 393216);       //  393216 -> 786432
  float*     bip     = (float*)(ws + 786432);          //    3072 -> 789504
  float*     hA      = (float*)(ws + 789504);          //  131072 -> 920576
  float*     hB      = (float*)(ws + 920576);          //  131072 -> 1051648
  int*       resT    = (int*)(ws + 1051648);           //  524288 -> 1575936
  unsigned*  rowsegs = (unsigned*)(ws + 1575936);      //  524288 -> 2100224
  unsigned*  rowcnt  = (unsigned*)(ws + 2100224);      //     512 -> 2100736
  unsigned*  lhist   = (unsigned*)(ws + 2100736);      //  524800 -> 2625536
  unsigned*  rowoff  = (unsigned*)(ws + 2625536);      //  524800 -> 3150336
  unsigned*  cursors = (unsigned*)(ws + 3150336);      //    4100 -> 3154560 (pad)
  unsigned*  Warr    = (unsigned*)(ws + 3154560);      //    4100 -> 3158784 (pad)
  unsigned*  nseg    = (unsigned*)(ws + 3158784);      //       4 -> 3158912 (pad)
  unsigned*  segs    = (unsigned*)(ws + 3158912);      //  524288 -> 3683200
  unsigned*  sstart  = (unsigned*)(ws + 3683200);      //   65536 -> 3748736
  unsigned*  preexS  = (unsigned*)(ws + 3748736);      //   65536 -> 3814272
  float*     dump    = (float*)(ws + 3814400);         // 1048576 -> 4862976
  const size_t gi_off = 4862976;                       // 256B aligned

  // gi (CH*128*768 f16) after gi_off
  int CH = T_DIM;
  while (CH > 256) {
    size_t need = gi_off + (size_t)CH * 128 * N3 * 2;
    if (need <= ws_size) break;
    CH >>= 1;
  }
  _Float16* gibuf = (_Float16*)(ws + gi_off);

  prep_whb<<<384, 256, 0, stream>>>(Wh, WhB);
  prep_witp<<<768, 256, 0, stream>>>(Wi, WiTp);
  prep_bip<<<1, 768, 0, stream>>>(bi, bip);
  init_h<<<128, 256, 0, stream>>>(h0, hA);
  seg_transpose<<<512, 256, 0, stream>>>(resets, resT);

  float* hbufs[2] = {hA, hB};
  for (int c = 0, t0 = 0; t0 < T_DIM; ++c, t0 += CH) {
    int steps = (t0 + CH <= T_DIM) ? CH : (T_DIM - t0);
    int M = steps * B_DIM;
    int Q = (M + NSTREAM - 1) / NSTREAM;   // equal-work quantum (32 @ CH=1024)
    if (Q < 1) Q = 1;

    gi_gemm<<<6 * (M / 128), 256, 0, stream>>>(
        ins + (size_t)t0 * B_DIM * H_DIM, WiTp, bip, gibuf, M);

    seg_extract<<<128, 256, 0, stream>>>(resT, t0, steps, rowsegs, rowcnt, lhist);
    seg_prefix2<<<1, 1024, 0, stream>>>(lhist, rowoff, cursors, Warr, nseg, steps);
    seg_scatter2<<<512, 256, 0, stream>>>(rowsegs, rowcnt, rowoff, cursors, segs);
    hipMemsetAsync(sstart, 0xFF, 131072, stream);   // sstart + preexS
    str_mark<<<512, 256, 0, stream>>>(segs, nseg, cursors, Warr, sstart, preexS, Q);

    scan_stream<<<NSTREAM / ROWS, 512, 0, stream>>>(
        (const _Float16*)WhB, gibuf, segs, sstart, preexS, nseg, bhn,
        hbufs[c & 1], hbufs[(c + 1) & 1], ys, hfin, dump, t0, steps, Q);
  }
}